// Round 1
// baseline (2609.479 us; speedup 1.0000x reference)
//
#include <hip/hip_runtime.h>

typedef _Float16 f16;
typedef _Float16 f16x8 __attribute__((ext_vector_type(8)));
typedef float    f32x4 __attribute__((ext_vector_type(4)));

#define NB   16       // batches
#define NP   8192     // points
#define NG   512      // groups (fps samples)
#define NM   32       // knn neighbors
#define ENC  384
#define NCHUNK 4
#define GPC  2048                 // groups per chunk
#define RPC  (GPC * NM)           // rows per chunk = 65536

// ---------------------------------------------------------------------------
// FPS: one block per batch; bitwise-exact distances (no fma contraction)
// ---------------------------------------------------------------------------
__global__ __launch_bounds__(1024) void fps_kernel(const float* __restrict__ pts,
                                                   float* __restrict__ centers) {
#pragma clang fp contract(off)
  const int b = blockIdx.x;
  const float* pb = pts + (size_t)b * NP * 3;
  const int t = threadIdx.x;
  const int lane = t & 63, wid = t >> 6;
  float px[8], py[8], pz[8], dd[8];
#pragma unroll
  for (int i = 0; i < 8; ++i) {
    int idx = t + i * 1024;
    px[i] = pb[idx * 3 + 0];
    py[i] = pb[idx * 3 + 1];
    pz[i] = pb[idx * 3 + 2];
    dd[i] = 1e10f;
  }
  __shared__ float swv[16];
  __shared__ int   swi[16];
  __shared__ int   s_next;
  int far = 0;
  for (int g = 0; g < NG; ++g) {
    float cx = pb[far * 3 + 0], cy = pb[far * 3 + 1], cz = pb[far * 3 + 2];
    if (t == 0) {
      float* c = centers + ((size_t)b * NG + g) * 3;
      c[0] = cx; c[1] = cy; c[2] = cz;
    }
    float best = -1.0f; int bi = 0;
#pragma unroll
    for (int i = 0; i < 8; ++i) {
      float dx = __fsub_rn(px[i], cx);
      float dy = __fsub_rn(py[i], cy);
      float dz = __fsub_rn(pz[i], cz);
      float d  = __fadd_rn(__fadd_rn(__fmul_rn(dx, dx), __fmul_rn(dy, dy)), __fmul_rn(dz, dz));
      dd[i] = fminf(dd[i], d);
      if (dd[i] > best) { best = dd[i]; bi = t + i * 1024; }   // ascending idx in-thread
    }
#pragma unroll
    for (int off = 32; off >= 1; off >>= 1) {
      float ov = __shfl_xor(best, off);
      int   oi = __shfl_xor(bi, off);
      if (ov > best || (ov == best && oi < bi)) { best = ov; bi = oi; }
    }
    if (lane == 0) { swv[wid] = best; swi[wid] = bi; }
    __syncthreads();
    if (t == 0) {
      float bv = swv[0]; int bidx = swi[0];
      for (int w = 1; w < 16; ++w) {
        float v = swv[w]; int ii = swi[w];
        if (v > bv || (v == bv && ii < bidx)) { bv = v; bidx = ii; }
      }
      s_next = bidx;
    }
    __syncthreads();
    far = s_next;
  }
}

// ---------------------------------------------------------------------------
// kNN: one block per group; top-32 smallest d2, tie-break lower index
// ---------------------------------------------------------------------------
__global__ __launch_bounds__(256) void knn_kernel(const float* __restrict__ pts,
                                                  const float* __restrict__ centers,
                                                  int* __restrict__ knn_idx) {
#pragma clang fp contract(off)
  const int gg = blockIdx.x;           // 0..8191
  const int b = gg >> 9;
  const float* pb = pts + (size_t)b * NP * 3;
  const float* c = centers + (size_t)gg * 3;
  const float cx = c[0], cy = c[1], cz = c[2];
  __shared__ float sd[NP];             // 32 KiB
  __shared__ float swv[4];
  __shared__ int   swi[4];
  __shared__ int   s_win;
  const int t = threadIdx.x, lane = t & 63, wid = t >> 6;
  float lmin = 3e38f; int lidx = 0;
#pragma unroll
  for (int i = 0; i < 32; ++i) {
    int idx = i * 256 + t;
    float dx = __fsub_rn(cx, pb[idx * 3 + 0]);
    float dy = __fsub_rn(cy, pb[idx * 3 + 1]);
    float dz = __fsub_rn(cz, pb[idx * 3 + 2]);
    float d  = __fadd_rn(__fadd_rn(__fmul_rn(dx, dx), __fmul_rn(dy, dy)), __fmul_rn(dz, dz));
    sd[idx] = d;
    if (d < lmin) { lmin = d; lidx = idx; }   // ascending idx in-thread
  }
  __syncthreads();
  int* outp = knn_idx + (size_t)gg * NM;
  for (int r = 0; r < NM; ++r) {
    float bv = lmin; int bidx = lidx;
#pragma unroll
    for (int off = 32; off >= 1; off >>= 1) {
      float ov = __shfl_xor(bv, off);
      int   oi = __shfl_xor(bidx, off);
      if (ov < bv || (ov == bv && oi < bidx)) { bv = ov; bidx = oi; }
    }
    if (lane == 0) { swv[wid] = bv; swi[wid] = bidx; }
    __syncthreads();
    if (t == 0) {
      float v0 = swv[0]; int i0 = swi[0];
      for (int w = 1; w < 4; ++w) {
        if (swv[w] < v0 || (swv[w] == v0 && swi[w] < i0)) { v0 = swv[w]; i0 = swi[w]; }
      }
      outp[r] = i0; s_win = i0;
    }
    __syncthreads();
    int win = s_win;
    if ((win & 255) == t) {
      sd[win] = 3e38f;
      lmin = 3e38f; lidx = 0;
#pragma unroll
      for (int i = 0; i < 32; ++i) {
        int idx = i * 256 + t;
        float d = sd[idx];
        if (d < lmin) { lmin = d; lidx = idx; }
      }
    }
  }
}

// ---------------------------------------------------------------------------
// weight quantize+transpose to f16:  W2T[256][128], W3bT[512][256], W4T[384][512]
// ---------------------------------------------------------------------------
__global__ void quant_kernel(const float* __restrict__ W2, const float* __restrict__ W3,
                             const float* __restrict__ W4, f16* __restrict__ W2T,
                             f16* __restrict__ W3bT, f16* __restrict__ W4T) {
  int i = blockIdx.x * 256 + threadIdx.x;
  if (i < 32768) {
    int n = i >> 7, k = i & 127;
    W2T[i] = (f16)W2[(size_t)k * 256 + n];
  } else if (i < 32768 + 131072) {
    int j = i - 32768;
    int n = j >> 8, k = j & 255;
    W3bT[j] = (f16)W3[(size_t)(256 + k) * 512 + n];
  } else if (i < 360448) {
    int j = i - 163840;
    int n = j >> 9, k = j & 511;
    W4T[j] = (f16)W4[(size_t)k * ENC + n];
  }
}

// ---------------------------------------------------------------------------
// L1: gather neighborhood + 3->128 MLP + BN + relu  -> f1 (chunk-local, f16)
// ---------------------------------------------------------------------------
__global__ __launch_bounds__(256) void l1_kernel(const float* __restrict__ pts,
                                                 const float* __restrict__ centers,
                                                 const int* __restrict__ knn_idx,
                                                 const float* __restrict__ W1, const float* __restrict__ b1,
                                                 const float* __restrict__ g1, const float* __restrict__ be1,
                                                 const float* __restrict__ m1, const float* __restrict__ v1,
                                                 f16* __restrict__ f1, int gg0) {
  const int gg = gg0 + blockIdx.x;
  const int b = gg >> 9;
  const int t = threadIdx.x;
  __shared__ float sn[NM][3];
  if (t < NM) {
    const float* c = centers + (size_t)gg * 3;
    int idx = knn_idx[(size_t)gg * NM + t];
    const float* p = pts + ((size_t)b * NP + idx) * 3;
    sn[t][0] = p[0] - c[0];
    sn[t][1] = p[1] - c[1];
    sn[t][2] = p[2] - c[2];
  }
  __syncthreads();
  size_t rowbase = (size_t)blockIdx.x * NM;
#pragma unroll
  for (int r = 0; r < 16; ++r) {
    int o = t + r * 256;
    int m = o >> 7, cc = o & 127;
    float a = sn[m][0] * W1[cc] + sn[m][1] * W1[128 + cc] + sn[m][2] * W1[256 + cc] + b1[cc];
    float s = g1[cc] * rsqrtf(v1[cc] + 1e-5f);
    a = (a - m1[cc]) * s + be1[cc];
    a = fmaxf(a, 0.0f);
    f1[(rowbase + m) * 128 + cc] = (f16)a;
  }
}

// ---------------------------------------------------------------------------
// fg = per-group max of f2 ; g3 = fg @ W3[0:256,:] + b3   (8 groups per block)
// ---------------------------------------------------------------------------
__global__ __launch_bounds__(256) void fg_g3_kernel(const f16* __restrict__ f2,
                                                    const float* __restrict__ W3,
                                                    const float* __restrict__ b3,
                                                    float* __restrict__ g3) {
  __shared__ float sfg[8][256];
  const int t = threadIdx.x;
  const int grp0 = blockIdx.x * 8;     // chunk-local group base
#pragma unroll
  for (int gi = 0; gi < 8; ++gi) {
    float mx = -3e38f;
    size_t rb = (size_t)(grp0 + gi) * NM;
    for (int r = 0; r < NM; ++r) mx = fmaxf(mx, (float)f2[(rb + r) * 256 + t]);
    sfg[gi][t] = mx;
  }
  __syncthreads();
  for (int half = 0; half < 2; ++half) {
    int n = t + half * 256;
    float acc[8];
#pragma unroll
    for (int gi = 0; gi < 8; ++gi) acc[gi] = b3[n];
#pragma unroll 4
    for (int k = 0; k < 256; ++k) {
      float w = W3[(size_t)k * 512 + n];
#pragma unroll
      for (int gi = 0; gi < 8; ++gi) acc[gi] += sfg[gi][k] * w;
    }
#pragma unroll
    for (int gi = 0; gi < 8; ++gi) g3[(size_t)(grp0 + gi) * 512 + n] = acc[gi];
  }
}

// ---------------------------------------------------------------------------
// Generic f16 MFMA GEMM: C[64 x 128 tile] = A[rows,K] @ BT[N,K]^T, f32 acc
// EPI 0: +b2 -> f16 out        (L2, N=256)
// EPI 1: +g3, BN2, relu -> f16 (L3, N=512)
// EPI 2: group-max +b4 -> f32  (L4, N=384, writes x)
// ---------------------------------------------------------------------------
template <int K, int EPI>
__global__ __launch_bounds__(256) void gemm_kernel(const f16* __restrict__ A,
                                                   const f16* __restrict__ BT,
                                                   float* __restrict__ outF32,
                                                   f16* __restrict__ outF16,
                                                   const float* __restrict__ e0,
                                                   const float* __restrict__ e1,
                                                   const float* __restrict__ e2,
                                                   const float* __restrict__ e3,
                                                   const float* __restrict__ e4,
                                                   int NTOT, int gg0) {
  __shared__ __align__(16) f16 sA[64 * 72];
  __shared__ __align__(16) f16 sB[128 * 72];
  const int t = threadIdx.x, lane = t & 63, wid = t >> 6;
  const int wrow = wid >> 1, wcol = wid & 1;
  const int l15 = lane & 15, lhi = lane >> 4;
  f32x4 acc[2][4];
#pragma unroll
  for (int m = 0; m < 2; ++m)
#pragma unroll
    for (int n = 0; n < 4; ++n) acc[m][n] = (f32x4){0.f, 0.f, 0.f, 0.f};

  const size_t arow0 = (size_t)blockIdx.x * 64;
  const int ncol0 = blockIdx.y * 128;
  const int ar = t >> 2, ac = (t & 3) * 16;
  const int br = t >> 1, bc = (t & 1) * 32;

  for (int kt = 0; kt < K; kt += 64) {
    const f16* ga = A + (arow0 + ar) * K + kt + ac;
    *(uint4*)&sA[ar * 72 + ac]     = *(const uint4*)ga;
    *(uint4*)&sA[ar * 72 + ac + 8] = *(const uint4*)(ga + 8);
    const f16* gb = BT + (size_t)(ncol0 + br) * K + kt + bc;
    *(uint4*)&sB[br * 72 + bc]      = *(const uint4*)gb;
    *(uint4*)&sB[br * 72 + bc + 8]  = *(const uint4*)(gb + 8);
    *(uint4*)&sB[br * 72 + bc + 16] = *(const uint4*)(gb + 16);
    *(uint4*)&sB[br * 72 + bc + 24] = *(const uint4*)(gb + 24);
    __syncthreads();
#pragma unroll
    for (int ks = 0; ks < 2; ++ks) {
      f16x8 af[2], bf[4];
#pragma unroll
      for (int m = 0; m < 2; ++m)
        af[m] = *(const f16x8*)&sA[(wrow * 32 + m * 16 + l15) * 72 + ks * 32 + lhi * 8];
#pragma unroll
      for (int n = 0; n < 4; ++n)
        bf[n] = *(const f16x8*)&sB[(wcol * 64 + n * 16 + l15) * 72 + ks * 32 + lhi * 8];
#pragma unroll
      for (int m = 0; m < 2; ++m)
#pragma unroll
        for (int n = 0; n < 4; ++n)
          acc[m][n] = __builtin_amdgcn_mfma_f32_16x16x32_f16(af[m], bf[n], acc[m][n], 0, 0, 0);
    }
    __syncthreads();
  }

  if (EPI == 0) {
#pragma unroll
    for (int m = 0; m < 2; ++m)
#pragma unroll
      for (int n = 0; n < 4; ++n) {
        int col = ncol0 + wcol * 64 + n * 16 + l15;
        float bias = e0[col];
#pragma unroll
        for (int i = 0; i < 4; ++i) {
          size_t row = arow0 + wrow * 32 + m * 16 + lhi * 4 + i;
          outF16[row * NTOT + col] = (f16)(acc[m][n][i] + bias);
        }
      }
  } else if (EPI == 1) {
    int grp = blockIdx.x * 2 + wrow;   // chunk-local group
#pragma unroll
    for (int n = 0; n < 4; ++n) {
      int col = ncol0 + wcol * 64 + n * 16 + l15;
      float s  = e1[col] * rsqrtf(e4[col] + 1e-5f);
      float sh = e2[col] - e3[col] * s;
      float gv = e0[(size_t)grp * 512 + col];
#pragma unroll
      for (int m = 0; m < 2; ++m)
#pragma unroll
        for (int i = 0; i < 4; ++i) {
          size_t row = arow0 + wrow * 32 + m * 16 + lhi * 4 + i;
          float v = (acc[m][n][i] + gv) * s + sh;
          v = fmaxf(v, 0.0f);
          outF16[row * NTOT + col] = (f16)v;
        }
    }
  } else {
    float vmax[4];
#pragma unroll
    for (int n = 0; n < 4; ++n) {
      float v = acc[0][n][0];
#pragma unroll
      for (int i = 1; i < 4; ++i) v = fmaxf(v, acc[0][n][i]);
#pragma unroll
      for (int i = 0; i < 4; ++i) v = fmaxf(v, acc[1][n][i]);
      v = fmaxf(v, __shfl_xor(v, 16));
      v = fmaxf(v, __shfl_xor(v, 32));
      vmax[n] = v;
    }
    if (lhi == 0) {
      size_t gg_glob = (size_t)gg0 + blockIdx.x * 2 + wrow;
#pragma unroll
      for (int n = 0; n < 4; ++n) {
        int col = ncol0 + wcol * 64 + n * 16 + l15;
        outF32[gg_glob * ENC + col] = vmax[n] + e0[col];
      }
    }
  }
}

// ---------------------------------------------------------------------------
// pos embed: gelu(center@Wp1+bp1)@Wp2+bp2  (32 groups per block)
// ---------------------------------------------------------------------------
__global__ __launch_bounds__(256) void pos_kernel(const float* __restrict__ centers,
                                                  const float* __restrict__ Wp1, const float* __restrict__ bp1,
                                                  const float* __restrict__ Wp2, const float* __restrict__ bp2,
                                                  float* __restrict__ out_pos) {
  __shared__ float sc[32][3];
  __shared__ float sh[32][128];
  const int t = threadIdx.x;
  const int gg0 = blockIdx.x * 32;
  if (t < 32) {
    const float* c = centers + (size_t)(gg0 + t) * 3;
    sc[t][0] = c[0]; sc[t][1] = c[1]; sc[t][2] = c[2];
  }
  __syncthreads();
#pragma unroll
  for (int r = 0; r < 16; ++r) {
    int o = t + r * 256;
    int m = o >> 7, c = o & 127;
    float x = sc[m][0] * Wp1[c] + sc[m][1] * Wp1[128 + c] + sc[m][2] * Wp1[256 + c] + bp1[c];
    float u = 0.7978845608028654f * (x + 0.044715f * x * x * x);
    sh[m][c] = 0.5f * x * (1.0f + tanhf(u));
  }
  __syncthreads();
  const int m = t >> 3, c0 = t & 7;
  int gg = gg0 + m;
  int bb = gg >> 9, g = gg & 511;
  float* orow = out_pos + ((size_t)bb * (NG + 1) + 1 + g) * ENC;
  for (int j = 0; j < 48; ++j) {
    int c = c0 + 8 * j;
    float a = bp2[c];
#pragma unroll 4
    for (int k = 0; k < 128; ++k) a += sh[m][k] * Wp2[(size_t)k * ENC + c];
    orow[c] = a;
  }
}

__global__ void cls_kernel(const float* __restrict__ cls_pos, float* __restrict__ out_pos) {
  out_pos[(size_t)blockIdx.x * (NG + 1) * ENC + threadIdx.x] = cls_pos[threadIdx.x];
}

// ---------------------------------------------------------------------------
extern "C" void kernel_launch(void* const* d_in, const int* in_sizes, int n_in,
                              void* d_out, int out_size, void* d_ws, size_t ws_size,
                              hipStream_t stream) {
  const float* pts = (const float*)d_in[0];
  const float* W1  = (const float*)d_in[1];
  const float* b1  = (const float*)d_in[2];
  const float* g1  = (const float*)d_in[3];
  const float* be1 = (const float*)d_in[4];
  const float* m1  = (const float*)d_in[5];
  const float* v1  = (const float*)d_in[6];
  const float* W2  = (const float*)d_in[7];
  const float* b2  = (const float*)d_in[8];
  const float* W3  = (const float*)d_in[9];
  const float* b3  = (const float*)d_in[10];
  const float* g2  = (const float*)d_in[11];
  const float* be2 = (const float*)d_in[12];
  const float* m2  = (const float*)d_in[13];
  const float* v2  = (const float*)d_in[14];
  const float* W4  = (const float*)d_in[15];
  const float* b4  = (const float*)d_in[16];
  const float* Wp1 = (const float*)d_in[17];
  const float* bp1 = (const float*)d_in[18];
  const float* Wp2 = (const float*)d_in[19];
  const float* bp2 = (const float*)d_in[20];
  const float* cls = (const float*)d_in[21];

  float* out_x   = (float*)d_out;                          // [16,512,384]
  float* out_pos = out_x + (size_t)NB * NG * ENC;          // [16,513,384]

  char* w = (char*)d_ws;
  auto alloc = [&](size_t bytes) {
    char* p = w;
    w += (bytes + 255) & ~(size_t)255;
    return p;
  };
  float* centers = (float*)alloc((size_t)NB * NG * 3 * 4);
  int*   knn     = (int*)alloc((size_t)NB * NG * NM * 4);
  f16*   W2T     = (f16*)alloc(32768 * 2);
  f16*   W3bT    = (f16*)alloc(131072 * 2);
  f16*   W4T     = (f16*)alloc(196608 * 2);
  f16*   f1      = (f16*)alloc((size_t)RPC * 128 * 2);
  f16*   f2      = (f16*)alloc((size_t)RPC * 256 * 2);
  f16*   f3      = (f16*)alloc((size_t)RPC * 512 * 2);
  float* g3      = (float*)alloc((size_t)GPC * 512 * 4);

  quant_kernel<<<dim3(1408), dim3(256), 0, stream>>>(W2, W3, W4, W2T, W3bT, W4T);
  fps_kernel<<<dim3(NB), dim3(1024), 0, stream>>>(pts, centers);
  knn_kernel<<<dim3(NB * NG), dim3(256), 0, stream>>>(pts, centers, knn);

  for (int ch = 0; ch < NCHUNK; ++ch) {
    int gg0 = ch * GPC;
    l1_kernel<<<dim3(GPC), dim3(256), 0, stream>>>(pts, centers, knn, W1, b1, g1, be1, m1, v1, f1, gg0);
    gemm_kernel<128, 0><<<dim3(RPC / 64, 2), dim3(256), 0, stream>>>(
        f1, W2T, nullptr, f2, b2, nullptr, nullptr, nullptr, nullptr, 256, gg0);
    fg_g3_kernel<<<dim3(GPC / 8), dim3(256), 0, stream>>>(f2, W3, b3, g3);
    gemm_kernel<256, 1><<<dim3(RPC / 64, 4), dim3(256), 0, stream>>>(
        f2, W3bT, nullptr, f3, g3, g2, be2, m2, v2, 512, gg0);
    gemm_kernel<512, 2><<<dim3(RPC / 64, 3), dim3(256), 0, stream>>>(
        f3, W4T, out_x, nullptr, b4, nullptr, nullptr, nullptr, nullptr, ENC, gg0);
  }

  pos_kernel<<<dim3(NB * NG / 32), dim3(256), 0, stream>>>(centers, Wp1, bp1, Wp2, bp2, out_pos);
  cls_kernel<<<dim3(NB), dim3(ENC), 0, stream>>>(cls, out_pos);
}